// Round 7
// baseline (181.430 us; speedup 1.0000x reference)
//
#include <hip/hip_runtime.h>
#include <hip/hip_bf16.h>
#include <stdint.h>

#define BB 8
#define CC 512
#define SS 1024
#define NH 8
#define DK 64
#define MM (BB*SS)      // 8192 rows
#define PQ 72           // P_lds pitch (elems): 144B rows, 16B-aligned
#define LNP 40          // xlnf raw[c][s] pitch in u16

typedef __attribute__((ext_vector_type(8))) short bf16x8;
typedef __attribute__((ext_vector_type(4))) float f32x4;

__device__ inline float b2f(unsigned short u) {
    union { unsigned int i; float f; } x; x.i = ((unsigned int)u) << 16; return x.f;
}
__device__ inline unsigned short f2b(float f) {
    union { float f; unsigned int i; } x; x.f = f;
    unsigned int r = (x.i + 0x7FFFu + ((x.i >> 16) & 1u)) >> 16;
    return (unsigned short)r;
}
__device__ inline unsigned int cvtpk(float lo, float hi) {
    unsigned int r;
    asm("v_cvt_pk_bf16_f32 %0, %1, %2" : "=v"(r) : "v"(lo), "v"(hi));
    return r;
}
__device__ inline f32x4 mfma16(bf16x8 a, bf16x8 b, f32x4 c) {
    return __builtin_amdgcn_mfma_f32_16x16x32_bf16(a, b, c, 0, 0, 0);
}
__device__ __forceinline__ void gload16(const void* g, void* l) {
    __builtin_amdgcn_global_load_lds(
        (const __attribute__((address_space(1))) void*)g,
        (__attribute__((address_space(3))) void*)l, 16, 0, 0);
}

// ---------------- weight transpose + bf16 cast: w[K][N] -> wT[N][K], 16B stores ------
__global__ void __launch_bounds__(256) wtrans_kernel(const float* __restrict__ wq,
                                                     const float* __restrict__ wk,
                                                     const float* __restrict__ wv,
                                                     const float* __restrict__ wo,
                                                     unsigned short* __restrict__ wT) {
    __shared__ float lds[64][65];
    const float* w = (blockIdx.z == 0) ? wq : (blockIdx.z == 1) ? wk : (blockIdx.z == 2) ? wv : wo;
    unsigned short* o = wT + (size_t)blockIdx.z * (512 * 512);
    const int n0 = blockIdx.x * 64, k0 = blockIdx.y * 64;
    const int t = threadIdx.x;
    {
        const int nl = (t & 15) * 4, kr = t >> 4;
#pragma unroll
        for (int i = 0; i < 4; ++i) {
            float4 v = *(const float4*)(w + (size_t)(k0 + kr + i * 16) * 512 + n0 + nl);
            lds[kr + i * 16][nl] = v.x; lds[kr + i * 16][nl + 1] = v.y;
            lds[kr + i * 16][nl + 2] = v.z; lds[kr + i * 16][nl + 3] = v.w;
        }
    }
    __syncthreads();
    {
        const int k8 = (t & 7) * 8, nr = t >> 3;
#pragma unroll
        for (int ii = 0; ii < 2; ++ii) {
            int n = nr + ii * 32;
            unsigned short pk[8];
#pragma unroll
            for (int e = 0; e < 8; ++e) pk[e] = f2b(lds[k8 + e][n]);
            *(uint4*)&o[(size_t)(n0 + n) * 512 + k0 + k8] = *(uint4*)pk;
        }
    }
}

// ---------------- fused transpose + LayerNorm: x fp32 [B][C][S] -> xt, tn bf16 -------
// Block: (b, 32 s-rows) x all 512 c. One global read of x; stats in fp32; outputs via
// LDS [c][s] staging (s-offset XOR-swizzled by c-bit6/7 to break transpose conflicts).
__global__ void __launch_bounds__(256) xlnf_kernel(const float* __restrict__ x,
                                                   const float* __restrict__ g,
                                                   const float* __restrict__ bta,
                                                   unsigned short* __restrict__ xt,
                                                   unsigned short* __restrict__ tn) {
    __shared__ unsigned short raw[512 * LNP];   // 40 KB, [c][s^swz]
    __shared__ float2 red[32][33];              // [cgroup][s]
    __shared__ float2 stf[32];
    const int b = blockIdx.y, s0 = blockIdx.x * 32;
    const int t = threadIdx.x;
    const int sl4 = (t & 7) * 4, crow = t >> 3;   // crow 0..31
    float sum[4] = {0.f, 0.f, 0.f, 0.f}, sq[4] = {0.f, 0.f, 0.f, 0.f};
#pragma unroll
    for (int ci = 0; ci < 16; ++ci) {
        const int c = crow + 32 * ci;
        float4 v = *(const float4*)(x + ((size_t)b * 512 + c) * 1024 + s0 + sl4);
        sum[0] += v.x; sq[0] += v.x * v.x;
        sum[1] += v.y; sq[1] += v.y * v.y;
        sum[2] += v.z; sq[2] += v.z * v.z;
        sum[3] += v.w; sq[3] += v.w * v.w;
        const int swz = ((c >> 6) & 3) << 3;
        uint2 pk;
        pk.x = (unsigned int)f2b(v.x) | ((unsigned int)f2b(v.y) << 16);
        pk.y = (unsigned int)f2b(v.z) | ((unsigned int)f2b(v.w) << 16);
        *(uint2*)&raw[c * LNP + (sl4 ^ swz)] = pk;
    }
#pragma unroll
    for (int e = 0; e < 4; ++e) red[crow][sl4 + e] = make_float2(sum[e], sq[e]);
    __syncthreads();
    if (t < 32) {
        float s = 0.f, q = 0.f;
#pragma unroll
        for (int cg = 0; cg < 32; ++cg) { s += red[cg][t].x; q += red[cg][t].y; }
        float mean = s * (1.f / 512.f);
        float var = q * (1.f / 512.f) - mean * mean;
        stf[t] = make_float2(mean, rsqrtf(var + 1e-5f));
    }
    __syncthreads();
    {
        const int srow = t >> 3, cb = (t & 7) * 64;
        const float2 st = stf[srow];
        const size_t orow = ((size_t)b * 1024 + s0 + srow) * 512;
#pragma unroll
        for (int cc = 0; cc < 64; cc += 8) {
            const int c0 = cb + cc;
            unsigned short rv[8], nv[8];
            const float4 g0 = *(const float4*)(g + c0), g1 = *(const float4*)(g + c0 + 4);
            const float4 b0 = *(const float4*)(bta + c0), b1 = *(const float4*)(bta + c0 + 4);
            const float gg[8] = {g0.x, g0.y, g0.z, g0.w, g1.x, g1.y, g1.z, g1.w};
            const float bb[8] = {b0.x, b0.y, b0.z, b0.w, b1.x, b1.y, b1.z, b1.w};
#pragma unroll
            for (int e = 0; e < 8; ++e) {
                const int c = c0 + e;
                const int swz = ((c >> 6) & 3) << 3;
                unsigned short u = raw[c * LNP + (srow ^ swz)];
                rv[e] = u;
                nv[e] = f2b((b2f(u) - st.x) * st.y * gg[e] + bb[e]);
            }
            *(uint4*)&xt[orow + c0] = *(uint4*)rv;
            *(uint4*)&tn[orow + c0] = *(uint4*)nv;
        }
    }
}

// ---------------- 128x128 GEMM core: global_load_lds + 2-phase double-buffer ---------
// SWAP=false: acc[i][j] = C[m][n], lane col n=l15, rows m=l4*4+r  (for transposed out)
// SWAP=true : operands swapped -> lane holds row m=l15, 4 CONTIGUOUS cols n=l4*4+r
template <bool SWAP>
__device__ inline void gemm_tile(const unsigned short* __restrict__ A,
                                 const unsigned short* __restrict__ Bt,
                                 int m0, int n0,
                                 unsigned short (*A_lds)[128 * 64],
                                 unsigned short (*B_lds)[128 * 64],
                                 f32x4 acc[4][4]) {
    const int t = threadIdx.x;
    const int lane = t & 63, w = t >> 6;
    const int l15 = lane & 15, l4 = lane >> 4;
    const int wm = (w >> 1) * 64, wn = (w & 1) * 64;
    auto STAGE = [&](int bi, int kt) {
#pragma unroll
        for (int i = 0; i < 4; ++i) {
            int chunk = i * 256 + t;
            int row = chunk >> 3, kc = (chunk & 7) * 8;
            gload16(A + (size_t)(m0 + row) * 512 + kt * 64 + kc, &A_lds[bi][chunk * 8]);
            gload16(Bt + (size_t)(n0 + row) * 512 + kt * 64 + kc, &B_lds[bi][chunk * 8]);
        }
    };
    STAGE(0, 0);
    __syncthreads();
#pragma unroll 1
    for (int kt = 0; kt < 8; ++kt) {
        const int bi = kt & 1;
        if (kt < 7) STAGE(bi ^ 1, kt + 1);   // issue next tile; drains at barrier
#pragma unroll
        for (int kk = 0; kk < 2; ++kk) {
            bf16x8 af[4], bfr[4];
#pragma unroll
            for (int i = 0; i < 4; ++i)
                af[i] = *(const bf16x8*)&A_lds[bi][(wm + i * 16 + l15) * 64 + kk * 32 + l4 * 8];
#pragma unroll
            for (int j = 0; j < 4; ++j)
                bfr[j] = *(const bf16x8*)&B_lds[bi][(wn + j * 16 + l15) * 64 + kk * 32 + l4 * 8];
#pragma unroll
            for (int i = 0; i < 4; ++i)
#pragma unroll
                for (int j = 0; j < 4; ++j)
                    acc[i][j] = SWAP ? mfma16(bfr[j], af[i], acc[i][j])
                                     : mfma16(af[i], bfr[j], acc[i][j]);
        }
        __syncthreads();   // vmcnt(0)+lgkmcnt(0): next tile resident, reads done
    }
}

// ---------------- QKV projection GEMM; V written pre-transposed [b][h][d][s] --------
__global__ void __launch_bounds__(256) gemm_qkv_kernel(const unsigned short* __restrict__ tn,
                                                       const unsigned short* __restrict__ wT,
                                                       const float* __restrict__ bq,
                                                       const float* __restrict__ bk,
                                                       const float* __restrict__ bv,
                                                       unsigned short* __restrict__ outbase) {
    __shared__ alignas(16) unsigned short A_lds[2][128 * 64];
    __shared__ alignas(16) unsigned short B_lds[2][128 * 64];
    const int z = blockIdx.z;
    const unsigned short* Bt = wT + (size_t)z * (512 * 512);
    const float* bias = (z == 0) ? bq : (z == 1) ? bk : bv;
    const int m0 = blockIdx.x * 128, n0 = blockIdx.y * 128;
    f32x4 acc[4][4];
    const f32x4 z4 = {0.f, 0.f, 0.f, 0.f};
#pragma unroll
    for (int i = 0; i < 4; ++i)
#pragma unroll
        for (int j = 0; j < 4; ++j) acc[i][j] = z4;
    const int lane = threadIdx.x & 63, w = threadIdx.x >> 6;
    const int l15 = lane & 15, l4 = lane >> 4;
    const int wm = (w >> 1) * 64, wn = (w & 1) * 64;
    if (z < 2) {
        // swapped operands: lane holds row m0+wm+i*16+l15, cols n0+wn+j*16+l4*4..+3
        gemm_tile<true>(tn, Bt, m0, n0, A_lds, B_lds, acc);
        unsigned short* out = outbase + (size_t)z * MM * 512;
        float4 bias4[4];
#pragma unroll
        for (int j = 0; j < 4; ++j)
            bias4[j] = *(const float4*)(bias + n0 + wn + j * 16 + l4 * 4);
#pragma unroll
        for (int i = 0; i < 4; ++i) {
            const size_t row = (size_t)(m0 + wm + i * 16 + l15);
#pragma unroll
            for (int j = 0; j < 4; ++j) {
                const int nc = n0 + wn + j * 16 + l4 * 4;
                uint2 pk;
                pk.x = (unsigned int)f2b(acc[i][j][0] + bias4[j].x) |
                       ((unsigned int)f2b(acc[i][j][1] + bias4[j].y) << 16);
                pk.y = (unsigned int)f2b(acc[i][j][2] + bias4[j].z) |
                       ((unsigned int)f2b(acc[i][j][3] + bias4[j].w) << 16);
                *(uint2*)&out[row * 512 + nc] = pk;
            }
        }
    } else {
        // unswapped: lane holds col n (=channel), 4 consecutive rows (=s) -> vt packed
        gemm_tile<false>(tn, Bt, m0, n0, A_lds, B_lds, acc);
        unsigned short* vt = outbase + (size_t)2 * MM * 512;
#pragma unroll
        for (int i = 0; i < 4; ++i)
#pragma unroll
            for (int j = 0; j < 4; ++j) {
                int col = n0 + wn + j * 16 + l15;
                float bcol = bias[col];
                int rowb = m0 + wm + i * 16 + l4 * 4;
                int bi = rowb >> 10, s0 = rowb & 1023;
                uint2 pk;
                pk.x = (unsigned int)f2b(acc[i][j][0] + bcol) |
                       ((unsigned int)f2b(acc[i][j][1] + bcol) << 16);
                pk.y = (unsigned int)f2b(acc[i][j][2] + bcol) |
                       ((unsigned int)f2b(acc[i][j][3] + bcol) << 16);
                *(uint2*)&vt[((size_t)bi * 512 + col) * 1024 + s0] = pk;
            }
    }
}

// ---------------- flash attention v6: 8-wave QBLK=128, LDS-staged K/V, XCD-grouped ---
__global__ void __launch_bounds__(512) attn_kernel(const unsigned short* __restrict__ q,
                                                   const unsigned short* __restrict__ k,
                                                   const unsigned short* __restrict__ vt,
                                                   unsigned short* __restrict__ o) {
    __shared__ alignas(16) unsigned short Kl[2][64 * 64];   // [key][d], source-swizzled
    __shared__ alignas(16) unsigned short Vl[2][64 * 64];   // [d][key], source-swizzled
    __shared__ alignas(16) unsigned short Pl[8][16 * PQ];   // per-wave P [q][key]
    const int pid = blockIdx.x;
    const int g = (pid >> 6) * 8 + (pid & 7);    // (b,h) group 0..63
    const int qt = (pid >> 3) & 7;               // q-tile 0..7 (128 rows each)
    const int b = g >> 3, h = g & 7;
    const int t = threadIdx.x, lane = t & 63, w = t >> 6;
    const int l15 = lane & 15, l4 = lane >> 4;

    const float QSC = 0.125f * 1.44269504f;
    const int qrow = qt * 128 + w * 16 + l15;
    const unsigned short* qp = q + ((size_t)(b * SS + qrow)) * 512 + h * 64;
    bf16x8 qf[2];
#pragma unroll
    for (int kk = 0; kk < 2; ++kk) {
        bf16x8 tmp = *(const bf16x8*)(qp + kk * 32 + l4 * 8);
#pragma unroll
        for (int e = 0; e < 8; ++e)
            tmp[e] = (short)f2b(b2f((unsigned short)tmp[e]) * QSC);
        qf[kk] = tmp;
    }

    const int srow = t >> 3;
    const int scb = ((t & 7) * 16) ^ ((srow & 7) << 4);
    const char* kptr = (const char*)(k + ((size_t)(b * SS) + srow) * 512 + h * 64) + scb;
    const char* vptr = (const char*)(vt + ((size_t)(b * NH + h) * DK + srow) * SS) + scb;

    float m_run = -1e30f, l_run = 0.f;
    f32x4 acc_o[4];
    const f32x4 z4 = {0.f, 0.f, 0.f, 0.f};
#pragma unroll
    for (int j = 0; j < 4; ++j) acc_o[j] = z4;

    gload16(kptr, &Kl[0][t * 8]);
    gload16(vptr, &Vl[0][t * 8]);
    kptr += 64 * 512 * 2;
    vptr += 64 * 2;
    __syncthreads();

#pragma unroll 1
    for (int kt = 0; kt < 16; ++kt) {
        const int bi = kt & 1;
        if (kt < 15) {
            gload16(kptr, &Kl[bi ^ 1][t * 8]);
            gload16(vptr, &Vl[bi ^ 1][t * 8]);
            kptr += 64 * 512 * 2;
            vptr += 64 * 2;
        }

        f32x4 sc[4];
#pragma unroll
        for (int j = 0; j < 4; ++j) sc[j] = z4;
#pragma unroll
        for (int kk = 0; kk < 2; ++kk)
#pragma unroll
            for (int j = 0; j < 4; ++j) {
                int row = j * 16 + l15;
                int cb = (kk * 64 + l4 * 16) ^ ((row & 7) << 4);
                bf16x8 kf = *(const bf16x8*)((const char*)Kl[bi] + row * 128 + cb);
                sc[j] = mfma16(kf, qf[kk], sc[j]);
            }

        float mx = fmaxf(fmaxf(sc[0][0], sc[0][1]), fmaxf(sc[0][2], sc[0][3]));
#pragma unroll
        for (int j = 1; j < 4; ++j)
            mx = fmaxf(mx, fmaxf(fmaxf(sc[j][0], sc[j][1]), fmaxf(sc[j][2], sc[j][3])));
        mx = fmaxf(mx, __shfl_xor(mx, 16));
        mx = fmaxf(mx, __shfl_xor(mx, 32));
        const float mnew = fmaxf(m_run, mx);
        const float scl = exp2f(m_run - mnew);
        m_run = mnew;

        float p[4][4], lsum = 0.f;
#pragma unroll
        for (int j = 0; j < 4; ++j)
#pragma unroll
            for (int r = 0; r < 4; ++r) {
                p[j][r] = exp2f(sc[j][r] - mnew);
                lsum += p[j][r];
            }
        l_run = l_run * scl + lsum;

#pragma unroll
        for (int j = 0; j < 4; ++j) {
            uint2 pk;
            pk.x = cvtpk(p[j][0], p[j][1]);
            pk.y = cvtpk(p[j][2], p[j][3]);
            *(uint2*)&Pl[w][l15 * PQ + j * 16 + l4 * 4] = pk;
        }

        float scl_r[4];
#pragma unroll
        for (int r = 0; r < 4; ++r) scl_r[r] = __shfl(scl, (l4 << 2) | r);
#pragma unroll
        for (int j = 0; j < 4; ++j)
#pragma unroll
            for (int r = 0; r < 4; ++r) acc_o[j][r] *= scl_r[r];

#pragma unroll
        for (int kk = 0; kk < 2; ++kk) {
            bf16x8 pf = *(const bf16x8*)&Pl[w][l15 * PQ + kk * 32 + l4 * 8];
#pragma unroll
            for (int j = 0; j < 4; ++j) {
                int row = j * 16 + l15;
                int cb = (kk * 64 + l4 * 16) ^ ((row & 7) << 4);
                bf16x8 vf = *(const bf16x8*)((const char*)Vl[bi] + row * 128 + cb);
                acc_o[j] = mfma16(pf, vf, acc_o[j]);
            }
        }

        __syncthreads();
    }

    float l_tot = l_run;
    l_tot += __shfl_xor(l_tot, 16);
    l_tot += __shfl_xor(l_tot, 32);
    float l_r[4];
#pragma unroll
    for (int r = 0; r < 4; ++r) l_r[r] = __shfl(l_tot, (l4 << 2) | r);

#pragma unroll
    for (int j = 0; j < 4; ++j)
#pragma unroll
        for (int r = 0; r < 4; ++r) {
            int row = qt * 128 + w * 16 + l4 * 4 + r;
            float val = acc_o[j][r] / l_r[r];
            o[((size_t)(b * SS + row)) * 512 + h * 64 + j * 16 + l15] = f2b(val);
        }
}

// ---------------- output projection + bias + residual (swapped: float4 stores) -------
__global__ void __launch_bounds__(256) gemm_out_kernel(const unsigned short* __restrict__ ao,
                                                       const unsigned short* __restrict__ woT,
                                                       const float* __restrict__ bo,
                                                       const unsigned short* __restrict__ xt,
                                                       float* __restrict__ out) {
    __shared__ alignas(16) unsigned short A_lds[2][128 * 64];
    __shared__ alignas(16) unsigned short B_lds[2][128 * 64];
    const int m0 = blockIdx.x * 128, n0 = blockIdx.y * 128;
    f32x4 acc[4][4];
    const f32x4 z4 = {0.f, 0.f, 0.f, 0.f};
#pragma unroll
    for (int i = 0; i < 4; ++i)
#pragma unroll
        for (int j = 0; j < 4; ++j) acc[i][j] = z4;
    gemm_tile<true>(ao, woT, m0, n0, A_lds, B_lds, acc);
    const int lane = threadIdx.x & 63, w = threadIdx.x >> 6;
    const int l15 = lane & 15, l4 = lane >> 4;
    const int wm = (w >> 1) * 64, wn = (w & 1) * 64;
    float4 bias4[4];
#pragma unroll
    for (int j = 0; j < 4; ++j)
        bias4[j] = *(const float4*)(bo + n0 + wn + j * 16 + l4 * 4);
#pragma unroll
    for (int i = 0; i < 4; ++i) {
        const size_t row = (size_t)(m0 + wm + i * 16 + l15);
#pragma unroll
        for (int j = 0; j < 4; ++j) {
            const int nc = n0 + wn + j * 16 + l4 * 4;
            uint2 rv = *(const uint2*)&xt[row * 512 + nc];
            float4 o4;
            o4.x = acc[i][j][0] + bias4[j].x + b2f((unsigned short)(rv.x & 0xffff));
            o4.y = acc[i][j][1] + bias4[j].y + b2f((unsigned short)(rv.x >> 16));
            o4.z = acc[i][j][2] + bias4[j].z + b2f((unsigned short)(rv.y & 0xffff));
            o4.w = acc[i][j][3] + bias4[j].w + b2f((unsigned short)(rv.y >> 16));
            *(float4*)&out[row * 512 + nc] = o4;
        }
    }
}

extern "C" void kernel_launch(void* const* d_in, const int* in_sizes, int n_in,
                              void* d_out, int out_size, void* d_ws, size_t ws_size,
                              hipStream_t stream) {
    const float* x   = (const float*)d_in[0];
    const float* wq  = (const float*)d_in[1];
    const float* bq  = (const float*)d_in[2];
    const float* wk  = (const float*)d_in[3];
    const float* bk  = (const float*)d_in[4];
    const float* wv  = (const float*)d_in[5];
    const float* bv  = (const float*)d_in[6];
    const float* lng = (const float*)d_in[7];
    const float* lnb = (const float*)d_in[8];
    const float* wo  = (const float*)d_in[9];
    const float* bo  = (const float*)d_in[10];
    float* out = (float*)d_out;

    unsigned short* ws  = (unsigned short*)d_ws;
    const size_t M1 = (size_t)1024 * 1024;
    unsigned short* tn   = ws;               // 4M elems (8 MB); reused as ao after qkv
    unsigned short* qkvb = ws + 4 * M1;      // q @ +0, k @ +4M, vt @ +8M (24 MB)
    unsigned short* wT   = ws + 16 * M1;     // 1M elems (2 MB)
    unsigned short* xt   = ws + 17 * M1;     // 4M elems (8 MB)
    unsigned short* ao   = tn;

    wtrans_kernel<<<dim3(8, 8, 4), 256, 0, stream>>>(wq, wk, wv, wo, wT);
    xlnf_kernel<<<dim3(32, 8), 256, 0, stream>>>(x, lng, lnb, xt, tn);
    gemm_qkv_kernel<<<dim3(64, 4, 3), 256, 0, stream>>>(tn, wT, bq, bk, bv, qkvb);
    attn_kernel<<<512, 512, 0, stream>>>(qkvb,
                                         qkvb + (size_t)MM * 512,
                                         qkvb + (size_t)2 * MM * 512,
                                         ao);
    gemm_out_kernel<<<dim3(64, 4), 256, 0, stream>>>(ao, wT + (size_t)3 * 512 * 512, bo, xt, out);
}

// Round 8
// 169.098 us; speedup vs baseline: 1.0729x; 1.0729x over previous
//
#include <hip/hip_runtime.h>
#include <hip/hip_bf16.h>
#include <stdint.h>

#define BB 8
#define CC 512
#define SS 1024
#define NH 8
#define DK 64
#define MM (BB*SS)      // 8192 rows
#define PQ 72           // P_lds pitch (elems): 144B rows, 16B-aligned
#define LNP 40          // xlnf raw[c][s] pitch in u16

typedef __attribute__((ext_vector_type(8))) short bf16x8;
typedef __attribute__((ext_vector_type(4))) float f32x4;

__device__ inline float b2f(unsigned short u) {
    union { unsigned int i; float f; } x; x.i = ((unsigned int)u) << 16; return x.f;
}
__device__ inline unsigned short f2b(float f) {
    union { float f; unsigned int i; } x; x.f = f;
    unsigned int r = (x.i + 0x7FFFu + ((x.i >> 16) & 1u)) >> 16;
    return (unsigned short)r;
}
__device__ inline unsigned int cvtpk(float lo, float hi) {
    unsigned int r;
    asm("v_cvt_pk_bf16_f32 %0, %1, %2" : "=v"(r) : "v"(lo), "v"(hi));
    return r;
}
__device__ inline f32x4 mfma16(bf16x8 a, bf16x8 b, f32x4 c) {
    return __builtin_amdgcn_mfma_f32_16x16x32_bf16(a, b, c, 0, 0, 0);
}
__device__ __forceinline__ void gload16(const void* g, void* l) {
    __builtin_amdgcn_global_load_lds(
        (const __attribute__((address_space(1))) void*)g,
        (__attribute__((address_space(3))) void*)l, 16, 0, 0);
}

// ---------------- prep: wtrans (blocks 0..255) U fused transpose+LN (256..511) -------
__global__ void __launch_bounds__(256) prep_kernel(const float* __restrict__ wq,
                                                   const float* __restrict__ wk,
                                                   const float* __restrict__ wv,
                                                   const float* __restrict__ wo,
                                                   unsigned short* __restrict__ wT,
                                                   const float* __restrict__ x,
                                                   const float* __restrict__ g,
                                                   const float* __restrict__ bta,
                                                   unsigned short* __restrict__ xt,
                                                   unsigned short* __restrict__ tn) {
    __shared__ alignas(16) char smem[49664];
    const int t = threadIdx.x;
    if (blockIdx.x < 256) {
        // ---- weight transpose + bf16 cast: w[K][N] -> wT[N][K] ----
        float (*lds)[65] = (float(*)[65])smem;
        const int bz = blockIdx.x >> 6, bx = (blockIdx.x >> 3) & 7, by = blockIdx.x & 7;
        const float* w = (bz == 0) ? wq : (bz == 1) ? wk : (bz == 2) ? wv : wo;
        unsigned short* o = wT + (size_t)bz * (512 * 512);
        const int n0 = bx * 64, k0 = by * 64;
        {
            const int nl = (t & 15) * 4, kr = t >> 4;
#pragma unroll
            for (int i = 0; i < 4; ++i) {
                float4 v = *(const float4*)(w + (size_t)(k0 + kr + i * 16) * 512 + n0 + nl);
                lds[kr + i * 16][nl] = v.x; lds[kr + i * 16][nl + 1] = v.y;
                lds[kr + i * 16][nl + 2] = v.z; lds[kr + i * 16][nl + 3] = v.w;
            }
        }
        __syncthreads();
        {
            const int k8 = (t & 7) * 8, nr = t >> 3;
#pragma unroll
            for (int ii = 0; ii < 2; ++ii) {
                int n = nr + ii * 32;
                unsigned short pk[8];
#pragma unroll
                for (int e = 0; e < 8; ++e) pk[e] = f2b(lds[k8 + e][n]);
                *(uint4*)&o[(size_t)(n0 + n) * 512 + k0 + k8] = *(uint4*)pk;
            }
        }
    } else {
        // ---- fused transpose + LayerNorm: x fp32 [B][C][S] -> xt, tn bf16 ----
        unsigned short* raw = (unsigned short*)smem;              // 40960 B
        float2 (*red)[33] = (float2(*)[33])(smem + 40960);        // 8448 B
        float2* stf = (float2*)(smem + 49408);                    // 256 B
        const int idx = blockIdx.x - 256;
        const int b = idx >> 5, s0 = (idx & 31) * 32;
        const int sl4 = (t & 7) * 4, crow = t >> 3;
        float sum[4] = {0.f, 0.f, 0.f, 0.f}, sq[4] = {0.f, 0.f, 0.f, 0.f};
#pragma unroll
        for (int ci = 0; ci < 16; ++ci) {
            const int c = crow + 32 * ci;
            float4 v = *(const float4*)(x + ((size_t)b * 512 + c) * 1024 + s0 + sl4);
            sum[0] += v.x; sq[0] += v.x * v.x;
            sum[1] += v.y; sq[1] += v.y * v.y;
            sum[2] += v.z; sq[2] += v.z * v.z;
            sum[3] += v.w; sq[3] += v.w * v.w;
            const int swz = ((c >> 6) & 3) << 3;
            uint2 pk;
            pk.x = (unsigned int)f2b(v.x) | ((unsigned int)f2b(v.y) << 16);
            pk.y = (unsigned int)f2b(v.z) | ((unsigned int)f2b(v.w) << 16);
            *(uint2*)&raw[c * LNP + (sl4 ^ swz)] = pk;
        }
#pragma unroll
        for (int e = 0; e < 4; ++e) red[crow][sl4 + e] = make_float2(sum[e], sq[e]);
        __syncthreads();
        if (t < 32) {
            float s = 0.f, q = 0.f;
#pragma unroll
            for (int cg = 0; cg < 32; ++cg) { s += red[cg][t].x; q += red[cg][t].y; }
            float mean = s * (1.f / 512.f);
            float var = q * (1.f / 512.f) - mean * mean;
            stf[t] = make_float2(mean, rsqrtf(var + 1e-5f));
        }
        __syncthreads();
        {
            const int srow = t >> 3, cb = (t & 7) * 64;
            const float2 st = stf[srow];
            const size_t orow = ((size_t)b * 1024 + s0 + srow) * 512;
#pragma unroll
            for (int cc = 0; cc < 64; cc += 8) {
                const int c0 = cb + cc;
                unsigned short rv[8], nv[8];
                const float4 g0 = *(const float4*)(g + c0), g1 = *(const float4*)(g + c0 + 4);
                const float4 b0 = *(const float4*)(bta + c0), b1 = *(const float4*)(bta + c0 + 4);
                const float gg[8] = {g0.x, g0.y, g0.z, g0.w, g1.x, g1.y, g1.z, g1.w};
                const float bb[8] = {b0.x, b0.y, b0.z, b0.w, b1.x, b1.y, b1.z, b1.w};
#pragma unroll
                for (int e = 0; e < 8; ++e) {
                    const int c = c0 + e;
                    const int swz = ((c >> 6) & 3) << 3;
                    unsigned short u = raw[c * LNP + (srow ^ swz)];
                    rv[e] = u;
                    nv[e] = f2b((b2f(u) - st.x) * st.y * gg[e] + bb[e]);
                }
                *(uint4*)&xt[orow + c0] = *(uint4*)rv;
                *(uint4*)&tn[orow + c0] = *(uint4*)nv;
            }
        }
    }
}

// ---------------- 128x128 GEMM core: gload_lds + dbuf + XOR-swizzled LDS -------------
// SWAP=true: lane holds row m=l15, 4 CONTIGUOUS cols n=l4*4..+3 (packed stores)
template <bool SWAP>
__device__ inline void gemm_tile(const unsigned short* __restrict__ A,
                                 const unsigned short* __restrict__ Bt,
                                 int m0, int n0,
                                 unsigned short (*A_lds)[128 * 64],
                                 unsigned short (*B_lds)[128 * 64],
                                 f32x4 acc[4][4]) {
    const int t = threadIdx.x;
    const int lane = t & 63, w = t >> 6;
    const int l15 = lane & 15, l4 = lane >> 4;
    const int wm = (w >> 1) * 64, wn = (w & 1) * 64;
    auto STAGE = [&](int bi, int kt) {
#pragma unroll
        for (int i = 0; i < 4; ++i) {
            int chunk = i * 256 + t;
            int row = chunk >> 3;
            int sb = ((chunk & 7) * 16) ^ ((row & 7) << 4);   // pre-swizzled source
            gload16((const char*)(A + (size_t)(m0 + row) * 512 + kt * 64) + sb,
                    &A_lds[bi][chunk * 8]);
            gload16((const char*)(Bt + (size_t)(n0 + row) * 512 + kt * 64) + sb,
                    &B_lds[bi][chunk * 8]);
        }
    };
    STAGE(0, 0);
    __syncthreads();
#pragma unroll 1
    for (int kt = 0; kt < 8; ++kt) {
        const int bi = kt & 1;
        if (kt < 7) STAGE(bi ^ 1, kt + 1);   // issue next tile; drains at barrier
#pragma unroll
        for (int kk = 0; kk < 2; ++kk) {
            bf16x8 af[4], bfr[4];
#pragma unroll
            for (int i = 0; i < 4; ++i) {
                int row = wm + i * 16 + l15;
                int cb = (kk * 64 + l4 * 16) ^ ((row & 7) << 4);
                af[i] = *(const bf16x8*)((const char*)A_lds[bi] + row * 128 + cb);
            }
#pragma unroll
            for (int j = 0; j < 4; ++j) {
                int row = wn + j * 16 + l15;
                int cb = (kk * 64 + l4 * 16) ^ ((row & 7) << 4);
                bfr[j] = *(const bf16x8*)((const char*)B_lds[bi] + row * 128 + cb);
            }
#pragma unroll
            for (int i = 0; i < 4; ++i)
#pragma unroll
                for (int j = 0; j < 4; ++j)
                    acc[i][j] = SWAP ? mfma16(bfr[j], af[i], acc[i][j])
                                     : mfma16(af[i], bfr[j], acc[i][j]);
        }
        __syncthreads();   // vmcnt(0)+lgkmcnt(0): next tile resident, reads done
    }
}

// ---------------- fused QKV GEMM: 128x64 tile, all 3 weights per block ---------------
// A staged once per K-step, 3 B-tiles staged alongside -> 48 MFMA per K-step per wave.
__global__ void __launch_bounds__(256) gemm_qkvf_kernel(const unsigned short* __restrict__ tn,
                                                        const unsigned short* __restrict__ wT,
                                                        const float* __restrict__ bq,
                                                        const float* __restrict__ bk,
                                                        const float* __restrict__ bv,
                                                        unsigned short* __restrict__ outbase) {
    __shared__ alignas(16) unsigned short A_lds[2][128 * 64];      // 32 KB
    __shared__ alignas(16) unsigned short B_lds[2][3][64 * 64];    // 48 KB
    const int m0 = blockIdx.x * 128, n0 = blockIdx.y * 64;
    const int t = threadIdx.x, lane = t & 63, w = t >> 6;
    const int l15 = lane & 15, l4 = lane >> 4;
    const int wm = w * 32;
    f32x4 acc[3][2][4];
    const f32x4 z4 = {0.f, 0.f, 0.f, 0.f};
#pragma unroll
    for (int z = 0; z < 3; ++z)
#pragma unroll
        for (int i = 0; i < 2; ++i)
#pragma unroll
            for (int j = 0; j < 4; ++j) acc[z][i][j] = z4;

    auto STAGE = [&](int bi, int kt) {
#pragma unroll
        for (int i = 0; i < 4; ++i) {
            int chunk = i * 256 + t;
            int row = chunk >> 3;
            int sb = ((chunk & 7) * 16) ^ ((row & 7) << 4);
            gload16((const char*)(tn + (size_t)(m0 + row) * 512 + kt * 64) + sb,
                    &A_lds[bi][chunk * 8]);
        }
#pragma unroll
        for (int z = 0; z < 3; ++z)
#pragma unroll
            for (int i = 0; i < 2; ++i) {
                int chunk = i * 256 + t;
                int row = chunk >> 3;
                int sb = ((chunk & 7) * 16) ^ ((row & 7) << 4);
                gload16((const char*)(wT + (size_t)z * 512 * 512 +
                                      (size_t)(n0 + row) * 512 + kt * 64) + sb,
                        &B_lds[bi][z][chunk * 8]);
            }
    };
    STAGE(0, 0);
    __syncthreads();
#pragma unroll 1
    for (int kt = 0; kt < 8; ++kt) {
        const int bi = kt & 1;
        if (kt < 7) STAGE(bi ^ 1, kt + 1);
#pragma unroll
        for (int kk = 0; kk < 2; ++kk) {
            bf16x8 af[2];
#pragma unroll
            for (int i = 0; i < 2; ++i) {
                int row = wm + i * 16 + l15;
                int cb = (kk * 64 + l4 * 16) ^ ((row & 7) << 4);
                af[i] = *(const bf16x8*)((const char*)A_lds[bi] + row * 128 + cb);
            }
#pragma unroll
            for (int z = 0; z < 3; ++z) {
                bf16x8 bfr[4];
#pragma unroll
                for (int j = 0; j < 4; ++j) {
                    int row = j * 16 + l15;
                    int cb = (kk * 64 + l4 * 16) ^ ((row & 7) << 4);
                    bfr[j] = *(const bf16x8*)((const char*)B_lds[bi][z] + row * 128 + cb);
                }
#pragma unroll
                for (int i = 0; i < 2; ++i)
#pragma unroll
                    for (int j = 0; j < 4; ++j)
                        acc[z][i][j] = (z < 2) ? mfma16(bfr[j], af[i], acc[z][i][j])
                                               : mfma16(af[i], bfr[j], acc[z][i][j]);
            }
        }
        __syncthreads();
    }
    // epilogue: q/k swapped (row=l15, packed cols); v unswapped -> vt scatter
#pragma unroll
    for (int z = 0; z < 2; ++z) {
        const float* bias = (z == 0) ? bq : bk;
        unsigned short* out = outbase + (size_t)z * MM * 512;
        float4 bias4[4];
#pragma unroll
        for (int j = 0; j < 4; ++j)
            bias4[j] = *(const float4*)(bias + n0 + j * 16 + l4 * 4);
#pragma unroll
        for (int i = 0; i < 2; ++i) {
            const size_t row = (size_t)(m0 + wm + i * 16 + l15);
#pragma unroll
            for (int j = 0; j < 4; ++j) {
                const int nc = n0 + j * 16 + l4 * 4;
                uint2 pk;
                pk.x = (unsigned int)f2b(acc[z][i][j][0] + bias4[j].x) |
                       ((unsigned int)f2b(acc[z][i][j][1] + bias4[j].y) << 16);
                pk.y = (unsigned int)f2b(acc[z][i][j][2] + bias4[j].z) |
                       ((unsigned int)f2b(acc[z][i][j][3] + bias4[j].w) << 16);
                *(uint2*)&out[row * 512 + nc] = pk;
            }
        }
    }
    {
        unsigned short* vt = outbase + (size_t)2 * MM * 512;
#pragma unroll
        for (int i = 0; i < 2; ++i)
#pragma unroll
            for (int j = 0; j < 4; ++j) {
                int col = n0 + j * 16 + l15;
                float bcol = bv[col];
                int rowb = m0 + wm + i * 16 + l4 * 4;
                int bi_ = rowb >> 10, s0 = rowb & 1023;
                uint2 pk;
                pk.x = (unsigned int)f2b(acc[2][i][j][0] + bcol) |
                       ((unsigned int)f2b(acc[2][i][j][1] + bcol) << 16);
                pk.y = (unsigned int)f2b(acc[2][i][j][2] + bcol) |
                       ((unsigned int)f2b(acc[2][i][j][3] + bcol) << 16);
                *(uint2*)&vt[((size_t)bi_ * 512 + col) * 1024 + s0] = pk;
            }
    }
}

// ---------------- flash attention v6: 8-wave QBLK=128, LDS-staged K/V, XCD-grouped ---
__global__ void __launch_bounds__(512) attn_kernel(const unsigned short* __restrict__ q,
                                                   const unsigned short* __restrict__ k,
                                                   const unsigned short* __restrict__ vt,
                                                   unsigned short* __restrict__ o) {
    __shared__ alignas(16) unsigned short Kl[2][64 * 64];   // [key][d], source-swizzled
    __shared__ alignas(16) unsigned short Vl[2][64 * 64];   // [d][key], source-swizzled
    __shared__ alignas(16) unsigned short Pl[8][16 * PQ];   // per-wave P [q][key]
    const int pid = blockIdx.x;
    const int g = (pid >> 6) * 8 + (pid & 7);    // (b,h) group 0..63
    const int qt = (pid >> 3) & 7;               // q-tile 0..7 (128 rows each)
    const int b = g >> 3, h = g & 7;
    const int t = threadIdx.x, lane = t & 63, w = t >> 6;
    const int l15 = lane & 15, l4 = lane >> 4;

    const float QSC = 0.125f * 1.44269504f;
    const int qrow = qt * 128 + w * 16 + l15;
    const unsigned short* qp = q + ((size_t)(b * SS + qrow)) * 512 + h * 64;
    bf16x8 qf[2];
#pragma unroll
    for (int kk = 0; kk < 2; ++kk) {
        bf16x8 tmp = *(const bf16x8*)(qp + kk * 32 + l4 * 8);
#pragma unroll
        for (int e = 0; e < 8; ++e)
            tmp[e] = (short)f2b(b2f((unsigned short)tmp[e]) * QSC);
        qf[kk] = tmp;
    }

    const int srow = t >> 3;
    const int scb = ((t & 7) * 16) ^ ((srow & 7) << 4);
    const char* kptr = (const char*)(k + ((size_t)(b * SS) + srow) * 512 + h * 64) + scb;
    const char* vptr = (const char*)(vt + ((size_t)(b * NH + h) * DK + srow) * SS) + scb;

    float m_run = -1e30f, l_run = 0.f;
    f32x4 acc_o[4];
    const f32x4 z4 = {0.f, 0.f, 0.f, 0.f};
#pragma unroll
    for (int j = 0; j < 4; ++j) acc_o[j] = z4;

    gload16(kptr, &Kl[0][t * 8]);
    gload16(vptr, &Vl[0][t * 8]);
    kptr += 64 * 512 * 2;
    vptr += 64 * 2;
    __syncthreads();

#pragma unroll 1
    for (int kt = 0; kt < 16; ++kt) {
        const int bi = kt & 1;
        if (kt < 15) {
            gload16(kptr, &Kl[bi ^ 1][t * 8]);
            gload16(vptr, &Vl[bi ^ 1][t * 8]);
            kptr += 64 * 512 * 2;
            vptr += 64 * 2;
        }

        f32x4 sc[4];
#pragma unroll
        for (int j = 0; j < 4; ++j) sc[j] = z4;
#pragma unroll
        for (int kk = 0; kk < 2; ++kk)
#pragma unroll
            for (int j = 0; j < 4; ++j) {
                int row = j * 16 + l15;
                int cb = (kk * 64 + l4 * 16) ^ ((row & 7) << 4);
                bf16x8 kf = *(const bf16x8*)((const char*)Kl[bi] + row * 128 + cb);
                sc[j] = mfma16(kf, qf[kk], sc[j]);
            }

        float mx = fmaxf(fmaxf(sc[0][0], sc[0][1]), fmaxf(sc[0][2], sc[0][3]));
#pragma unroll
        for (int j = 1; j < 4; ++j)
            mx = fmaxf(mx, fmaxf(fmaxf(sc[j][0], sc[j][1]), fmaxf(sc[j][2], sc[j][3])));
        mx = fmaxf(mx, __shfl_xor(mx, 16));
        mx = fmaxf(mx, __shfl_xor(mx, 32));
        const float mnew = fmaxf(m_run, mx);
        const float scl = exp2f(m_run - mnew);
        m_run = mnew;

        float p[4][4], lsum = 0.f;
#pragma unroll
        for (int j = 0; j < 4; ++j)
#pragma unroll
            for (int r = 0; r < 4; ++r) {
                p[j][r] = exp2f(sc[j][r] - mnew);
                lsum += p[j][r];
            }
        l_run = l_run * scl + lsum;

#pragma unroll
        for (int j = 0; j < 4; ++j) {
            uint2 pk;
            pk.x = cvtpk(p[j][0], p[j][1]);
            pk.y = cvtpk(p[j][2], p[j][3]);
            *(uint2*)&Pl[w][l15 * PQ + j * 16 + l4 * 4] = pk;
        }

        float scl_r[4];
#pragma unroll
        for (int r = 0; r < 4; ++r) scl_r[r] = __shfl(scl, (l4 << 2) | r);
#pragma unroll
        for (int j = 0; j < 4; ++j)
#pragma unroll
            for (int r = 0; r < 4; ++r) acc_o[j][r] *= scl_r[r];

#pragma unroll
        for (int kk = 0; kk < 2; ++kk) {
            bf16x8 pf = *(const bf16x8*)&Pl[w][l15 * PQ + kk * 32 + l4 * 8];
#pragma unroll
            for (int j = 0; j < 4; ++j) {
                int row = j * 16 + l15;
                int cb = (kk * 64 + l4 * 16) ^ ((row & 7) << 4);
                bf16x8 vf = *(const bf16x8*)((const char*)Vl[bi] + row * 128 + cb);
                acc_o[j] = mfma16(pf, vf, acc_o[j]);
            }
        }

        __syncthreads();
    }

    float l_tot = l_run;
    l_tot += __shfl_xor(l_tot, 16);
    l_tot += __shfl_xor(l_tot, 32);
    float l_r[4];
#pragma unroll
    for (int r = 0; r < 4; ++r) l_r[r] = __shfl(l_tot, (l4 << 2) | r);

#pragma unroll
    for (int j = 0; j < 4; ++j)
#pragma unroll
        for (int r = 0; r < 4; ++r) {
            int row = qt * 128 + w * 16 + l4 * 4 + r;
            float val = acc_o[j][r] / l_r[r];
            o[((size_t)(b * SS + row)) * 512 + h * 64 + j * 16 + l15] = f2b(val);
        }
}

// ---------------- output projection + bias + residual (swapped: float4 stores) -------
__global__ void __launch_bounds__(256) gemm_out_kernel(const unsigned short* __restrict__ ao,
                                                       const unsigned short* __restrict__ woT,
                                                       const float* __restrict__ bo,
                                                       const unsigned short* __restrict__ xt,
                                                       float* __restrict__ out) {
    __shared__ alignas(16) unsigned short A_lds[2][128 * 64];
    __shared__ alignas(16) unsigned short B_lds[2][128 * 64];
    const int m0 = blockIdx.x * 128, n0 = blockIdx.y * 128;
    f32x4 acc[4][4];
    const f32x4 z4 = {0.f, 0.f, 0.f, 0.f};
#pragma unroll
    for (int i = 0; i < 4; ++i)
#pragma unroll
        for (int j = 0; j < 4; ++j) acc[i][j] = z4;
    gemm_tile<true>(ao, woT, m0, n0, A_lds, B_lds, acc);
    const int lane = threadIdx.x & 63, w = threadIdx.x >> 6;
    const int l15 = lane & 15, l4 = lane >> 4;
    const int wm = (w >> 1) * 64, wn = (w & 1) * 64;
    float4 bias4[4];
#pragma unroll
    for (int j = 0; j < 4; ++j)
        bias4[j] = *(const float4*)(bo + n0 + wn + j * 16 + l4 * 4);
#pragma unroll
    for (int i = 0; i < 4; ++i) {
        const size_t row = (size_t)(m0 + wm + i * 16 + l15);
#pragma unroll
        for (int j = 0; j < 4; ++j) {
            const int nc = n0 + wn + j * 16 + l4 * 4;
            uint2 rv = *(const uint2*)&xt[row * 512 + nc];
            float4 o4;
            o4.x = acc[i][j][0] + bias4[j].x + b2f((unsigned short)(rv.x & 0xffff));
            o4.y = acc[i][j][1] + bias4[j].y + b2f((unsigned short)(rv.x >> 16));
            o4.z = acc[i][j][2] + bias4[j].z + b2f((unsigned short)(rv.y & 0xffff));
            o4.w = acc[i][j][3] + bias4[j].w + b2f((unsigned short)(rv.y >> 16));
            *(float4*)&out[row * 512 + nc] = o4;
        }
    }
}

extern "C" void kernel_launch(void* const* d_in, const int* in_sizes, int n_in,
                              void* d_out, int out_size, void* d_ws, size_t ws_size,
                              hipStream_t stream) {
    const float* x   = (const float*)d_in[0];
    const float* wq  = (const float*)d_in[1];
    const float* bq  = (const float*)d_in[2];
    const float* wk  = (const float*)d_in[3];
    const float* bk  = (const float*)d_in[4];
    const float* wv  = (const float*)d_in[5];
    const float* bv  = (const float*)d_in[6];
    const float* lng = (const float*)d_in[7];
    const float* lnb = (const float*)d_in[8];
    const float* wo  = (const float*)d_in[9];
    const float* bo  = (const float*)d_in[10];
    float* out = (float*)d_out;

    unsigned short* ws  = (unsigned short*)d_ws;
    const size_t M1 = (size_t)1024 * 1024;
    unsigned short* tn   = ws;               // 4M elems (8 MB); reused as ao after qkv
    unsigned short* qkvb = ws + 4 * M1;      // q @ +0, k @ +4M, vt @ +8M (24 MB)
    unsigned short* wT   = ws + 16 * M1;     // 1M elems (2 MB)
    unsigned short* xt   = ws + 17 * M1;     // 4M elems (8 MB)
    unsigned short* ao   = tn;

    prep_kernel<<<512, 256, 0, stream>>>(wq, wk, wv, wo, wT, x, lng, lnb, xt, tn);
    gemm_qkvf_kernel<<<dim3(64, 8), 256, 0, stream>>>(tn, wT, bq, bk, bv, qkvb);
    attn_kernel<<<512, 512, 0, stream>>>(qkvb,
                                         qkvb + (size_t)MM * 512,
                                         qkvb + (size_t)2 * MM * 512,
                                         ao);
    gemm_out_kernel<<<dim3(64, 4), 256, 0, stream>>>(ao, wT + (size_t)3 * 512 * 512, bo, xt, out);
}

// Round 9
// 160.236 us; speedup vs baseline: 1.1323x; 1.0553x over previous
//
#include <hip/hip_runtime.h>
#include <hip/hip_bf16.h>
#include <stdint.h>

#define BB 8
#define CC 512
#define SS 1024
#define NH 8
#define DK 64
#define MM (BB*SS)      // 8192 rows
#define PQ 72           // P_lds pitch (elems): 144B rows, 16B-aligned
#define LNP 40          // xlnf raw[c][s] pitch in u16

typedef __attribute__((ext_vector_type(8))) short bf16x8;
typedef __attribute__((ext_vector_type(4))) float f32x4;

__device__ inline float b2f(unsigned short u) {
    union { unsigned int i; float f; } x; x.i = ((unsigned int)u) << 16; return x.f;
}
__device__ inline unsigned short f2b(float f) {
    union { float f; unsigned int i; } x; x.f = f;
    unsigned int r = (x.i + 0x7FFFu + ((x.i >> 16) & 1u)) >> 16;
    return (unsigned short)r;
}
__device__ inline unsigned int cvtpk(float lo, float hi) {
    unsigned int r;
    asm("v_cvt_pk_bf16_f32 %0, %1, %2" : "=v"(r) : "v"(lo), "v"(hi));
    return r;
}
// native 2^x (v_exp_f32): 1 instr vs ~12 for precise exp2f; denorm-flush OK for softmax
__device__ inline float fexp2(float x) { return __builtin_amdgcn_exp2f(x); }
__device__ inline f32x4 mfma16(bf16x8 a, bf16x8 b, f32x4 c) {
    return __builtin_amdgcn_mfma_f32_16x16x32_bf16(a, b, c, 0, 0, 0);
}
__device__ __forceinline__ void gload16(const void* g, void* l) {
    __builtin_amdgcn_global_load_lds(
        (const __attribute__((address_space(1))) void*)g,
        (__attribute__((address_space(3))) void*)l, 16, 0, 0);
}

// ---------------- prep: wtrans (blocks 0..255) U fused transpose+LN (256..511) -------
__global__ void __launch_bounds__(256) prep_kernel(const float* __restrict__ wq,
                                                   const float* __restrict__ wk,
                                                   const float* __restrict__ wv,
                                                   const float* __restrict__ wo,
                                                   unsigned short* __restrict__ wT,
                                                   const float* __restrict__ x,
                                                   const float* __restrict__ g,
                                                   const float* __restrict__ bta,
                                                   unsigned short* __restrict__ xt,
                                                   unsigned short* __restrict__ tn) {
    __shared__ alignas(16) char smem[49664];
    const int t = threadIdx.x;
    if (blockIdx.x < 256) {
        float (*lds)[65] = (float(*)[65])smem;
        const int bz = blockIdx.x >> 6, bx = (blockIdx.x >> 3) & 7, by = blockIdx.x & 7;
        const float* w = (bz == 0) ? wq : (bz == 1) ? wk : (bz == 2) ? wv : wo;
        unsigned short* o = wT + (size_t)bz * (512 * 512);
        const int n0 = bx * 64, k0 = by * 64;
        {
            const int nl = (t & 15) * 4, kr = t >> 4;
#pragma unroll
            for (int i = 0; i < 4; ++i) {
                float4 v = *(const float4*)(w + (size_t)(k0 + kr + i * 16) * 512 + n0 + nl);
                lds[kr + i * 16][nl] = v.x; lds[kr + i * 16][nl + 1] = v.y;
                lds[kr + i * 16][nl + 2] = v.z; lds[kr + i * 16][nl + 3] = v.w;
            }
        }
        __syncthreads();
        {
            const int k8 = (t & 7) * 8, nr = t >> 3;
#pragma unroll
            for (int ii = 0; ii < 2; ++ii) {
                int n = nr + ii * 32;
                unsigned short pk[8];
#pragma unroll
                for (int e = 0; e < 8; ++e) pk[e] = f2b(lds[k8 + e][n]);
                *(uint4*)&o[(size_t)(n0 + n) * 512 + k0 + k8] = *(uint4*)pk;
            }
        }
    } else {
        unsigned short* raw = (unsigned short*)smem;              // 40960 B
        float2 (*red)[33] = (float2(*)[33])(smem + 40960);        // 8448 B
        float2* stf = (float2*)(smem + 49408);                    // 256 B
        const int idx = blockIdx.x - 256;
        const int b = idx >> 5, s0 = (idx & 31) * 32;
        const int sl4 = (t & 7) * 4, crow = t >> 3;
        float sum[4] = {0.f, 0.f, 0.f, 0.f}, sq[4] = {0.f, 0.f, 0.f, 0.f};
#pragma unroll
        for (int ci = 0; ci < 16; ++ci) {
            const int c = crow + 32 * ci;
            float4 v = *(const float4*)(x + ((size_t)b * 512 + c) * 1024 + s0 + sl4);
            sum[0] += v.x; sq[0] += v.x * v.x;
            sum[1] += v.y; sq[1] += v.y * v.y;
            sum[2] += v.z; sq[2] += v.z * v.z;
            sum[3] += v.w; sq[3] += v.w * v.w;
            const int swz = ((c >> 6) & 3) << 3;
            uint2 pk;
            pk.x = (unsigned int)f2b(v.x) | ((unsigned int)f2b(v.y) << 16);
            pk.y = (unsigned int)f2b(v.z) | ((unsigned int)f2b(v.w) << 16);
            *(uint2*)&raw[c * LNP + (sl4 ^ swz)] = pk;
        }
#pragma unroll
        for (int e = 0; e < 4; ++e) red[crow][sl4 + e] = make_float2(sum[e], sq[e]);
        __syncthreads();
        if (t < 32) {
            float s = 0.f, q = 0.f;
#pragma unroll
            for (int cg = 0; cg < 32; ++cg) { s += red[cg][t].x; q += red[cg][t].y; }
            float mean = s * (1.f / 512.f);
            float var = q * (1.f / 512.f) - mean * mean;
            stf[t] = make_float2(mean, rsqrtf(var + 1e-5f));
        }
        __syncthreads();
        {
            const int srow = t >> 3, cb = (t & 7) * 64;
            const float2 st = stf[srow];
            const size_t orow = ((size_t)b * 1024 + s0 + srow) * 512;
#pragma unroll
            for (int cc = 0; cc < 64; cc += 8) {
                const int c0 = cb + cc;
                unsigned short rv[8], nv[8];
                const float4 g0 = *(const float4*)(g + c0), g1 = *(const float4*)(g + c0 + 4);
                const float4 b0 = *(const float4*)(bta + c0), b1 = *(const float4*)(bta + c0 + 4);
                const float gg[8] = {g0.x, g0.y, g0.z, g0.w, g1.x, g1.y, g1.z, g1.w};
                const float bb[8] = {b0.x, b0.y, b0.z, b0.w, b1.x, b1.y, b1.z, b1.w};
#pragma unroll
                for (int e = 0; e < 8; ++e) {
                    const int c = c0 + e;
                    const int swz = ((c >> 6) & 3) << 3;
                    unsigned short u = raw[c * LNP + (srow ^ swz)];
                    rv[e] = u;
                    nv[e] = f2b((b2f(u) - st.x) * st.y * gg[e] + bb[e]);
                }
                *(uint4*)&xt[orow + c0] = *(uint4*)rv;
                *(uint4*)&tn[orow + c0] = *(uint4*)nv;
            }
        }
    }
}

// ---------------- 128x128 GEMM core: gload_lds + dbuf + XOR-swizzled LDS -------------
template <bool SWAP>
__device__ inline void gemm_tile(const unsigned short* __restrict__ A,
                                 const unsigned short* __restrict__ Bt,
                                 int m0, int n0,
                                 unsigned short (*A_lds)[128 * 64],
                                 unsigned short (*B_lds)[128 * 64],
                                 f32x4 acc[4][4]) {
    const int t = threadIdx.x;
    const int lane = t & 63, w = t >> 6;
    const int l15 = lane & 15, l4 = lane >> 4;
    const int wm = (w >> 1) * 64, wn = (w & 1) * 64;
    auto STAGE = [&](int bi, int kt) {
#pragma unroll
        for (int i = 0; i < 4; ++i) {
            int chunk = i * 256 + t;
            int row = chunk >> 3;
            int sb = ((chunk & 7) * 16) ^ ((row & 7) << 4);
            gload16((const char*)(A + (size_t)(m0 + row) * 512 + kt * 64) + sb,
                    &A_lds[bi][chunk * 8]);
            gload16((const char*)(Bt + (size_t)(n0 + row) * 512 + kt * 64) + sb,
                    &B_lds[bi][chunk * 8]);
        }
    };
    STAGE(0, 0);
    __syncthreads();
#pragma unroll 1
    for (int kt = 0; kt < 8; ++kt) {
        const int bi = kt & 1;
        if (kt < 7) STAGE(bi ^ 1, kt + 1);
#pragma unroll
        for (int kk = 0; kk < 2; ++kk) {
            bf16x8 af[4], bfr[4];
#pragma unroll
            for (int i = 0; i < 4; ++i) {
                int row = wm + i * 16 + l15;
                int cb = (kk * 64 + l4 * 16) ^ ((row & 7) << 4);
                af[i] = *(const bf16x8*)((const char*)A_lds[bi] + row * 128 + cb);
            }
#pragma unroll
            for (int j = 0; j < 4; ++j) {
                int row = wn + j * 16 + l15;
                int cb = (kk * 64 + l4 * 16) ^ ((row & 7) << 4);
                bfr[j] = *(const bf16x8*)((const char*)B_lds[bi] + row * 128 + cb);
            }
#pragma unroll
            for (int i = 0; i < 4; ++i)
#pragma unroll
                for (int j = 0; j < 4; ++j)
                    acc[i][j] = SWAP ? mfma16(bfr[j], af[i], acc[i][j])
                                     : mfma16(af[i], bfr[j], acc[i][j]);
        }
        __syncthreads();
    }
}

// ---------------- fused QKV GEMM: 128x64 tile, XCD-grouped by m-tile -----------------
__global__ void __launch_bounds__(256) gemm_qkvf_kernel(const unsigned short* __restrict__ tn,
                                                        const unsigned short* __restrict__ wT,
                                                        const float* __restrict__ bq,
                                                        const float* __restrict__ bk,
                                                        const float* __restrict__ bv,
                                                        unsigned short* __restrict__ outbase) {
    __shared__ alignas(16) unsigned short A_lds[2][128 * 64];      // 32 KB
    __shared__ alignas(16) unsigned short B_lds[2][3][64 * 64];    // 48 KB
    // XCD grouping: all 8 n-blocks of one m-tile run on one XCD -> A-tile L2-local.
    const int pid = blockIdx.x;                  // 0..511
    const int xcd = pid & 7, rest = pid >> 3;    // rest 0..63
    const int n0 = (rest & 7) * 64;
    const int m0 = (xcd + (rest >> 3) * 8) * 128;
    const int t = threadIdx.x, lane = t & 63, w = t >> 6;
    const int l15 = lane & 15, l4 = lane >> 4;
    const int wm = w * 32;
    f32x4 acc[3][2][4];
    const f32x4 z4 = {0.f, 0.f, 0.f, 0.f};
#pragma unroll
    for (int z = 0; z < 3; ++z)
#pragma unroll
        for (int i = 0; i < 2; ++i)
#pragma unroll
            for (int j = 0; j < 4; ++j) acc[z][i][j] = z4;

    auto STAGE = [&](int bi, int kt) {
#pragma unroll
        for (int i = 0; i < 4; ++i) {
            int chunk = i * 256 + t;
            int row = chunk >> 3;
            int sb = ((chunk & 7) * 16) ^ ((row & 7) << 4);
            gload16((const char*)(tn + (size_t)(m0 + row) * 512 + kt * 64) + sb,
                    &A_lds[bi][chunk * 8]);
        }
#pragma unroll
        for (int z = 0; z < 3; ++z)
#pragma unroll
            for (int i = 0; i < 2; ++i) {
                int chunk = i * 256 + t;
                int row = chunk >> 3;
                int sb = ((chunk & 7) * 16) ^ ((row & 7) << 4);
                gload16((const char*)(wT + (size_t)z * 512 * 512 +
                                      (size_t)(n0 + row) * 512 + kt * 64) + sb,
                        &B_lds[bi][z][chunk * 8]);
            }
    };
    STAGE(0, 0);
    __syncthreads();
#pragma unroll 1
    for (int kt = 0; kt < 8; ++kt) {
        const int bi = kt & 1;
        if (kt < 7) STAGE(bi ^ 1, kt + 1);
#pragma unroll
        for (int kk = 0; kk < 2; ++kk) {
            bf16x8 af[2];
#pragma unroll
            for (int i = 0; i < 2; ++i) {
                int row = wm + i * 16 + l15;
                int cb = (kk * 64 + l4 * 16) ^ ((row & 7) << 4);
                af[i] = *(const bf16x8*)((const char*)A_lds[bi] + row * 128 + cb);
            }
#pragma unroll
            for (int z = 0; z < 3; ++z) {
                bf16x8 bfr[4];
#pragma unroll
                for (int j = 0; j < 4; ++j) {
                    int row = j * 16 + l15;
                    int cb = (kk * 64 + l4 * 16) ^ ((row & 7) << 4);
                    bfr[j] = *(const bf16x8*)((const char*)B_lds[bi][z] + row * 128 + cb);
                }
#pragma unroll
                for (int i = 0; i < 2; ++i)
#pragma unroll
                    for (int j = 0; j < 4; ++j)
                        acc[z][i][j] = (z < 2) ? mfma16(bfr[j], af[i], acc[z][i][j])
                                               : mfma16(af[i], bfr[j], acc[z][i][j]);
            }
        }
        __syncthreads();
    }
#pragma unroll
    for (int z = 0; z < 2; ++z) {
        const float* bias = (z == 0) ? bq : bk;
        unsigned short* out = outbase + (size_t)z * MM * 512;
        float4 bias4[4];
#pragma unroll
        for (int j = 0; j < 4; ++j)
            bias4[j] = *(const float4*)(bias + n0 + j * 16 + l4 * 4);
#pragma unroll
        for (int i = 0; i < 2; ++i) {
            const size_t row = (size_t)(m0 + wm + i * 16 + l15);
#pragma unroll
            for (int j = 0; j < 4; ++j) {
                const int nc = n0 + j * 16 + l4 * 4;
                uint2 pk;
                pk.x = (unsigned int)f2b(acc[z][i][j][0] + bias4[j].x) |
                       ((unsigned int)f2b(acc[z][i][j][1] + bias4[j].y) << 16);
                pk.y = (unsigned int)f2b(acc[z][i][j][2] + bias4[j].z) |
                       ((unsigned int)f2b(acc[z][i][j][3] + bias4[j].w) << 16);
                *(uint2*)&out[row * 512 + nc] = pk;
            }
        }
    }
    {
        unsigned short* vt = outbase + (size_t)2 * MM * 512;
#pragma unroll
        for (int i = 0; i < 2; ++i)
#pragma unroll
            for (int j = 0; j < 4; ++j) {
                int col = n0 + j * 16 + l15;
                float bcol = bv[col];
                int rowb = m0 + wm + i * 16 + l4 * 4;
                int bi_ = rowb >> 10, s0 = rowb & 1023;
                uint2 pk;
                pk.x = (unsigned int)f2b(acc[2][i][j][0] + bcol) |
                       ((unsigned int)f2b(acc[2][i][j][1] + bcol) << 16);
                pk.y = (unsigned int)f2b(acc[2][i][j][2] + bcol) |
                       ((unsigned int)f2b(acc[2][i][j][3] + bcol) << 16);
                *(uint2*)&vt[((size_t)bi_ * 512 + col) * 1024 + s0] = pk;
            }
    }
}

// ---------------- flash attention v7: native exp2, 8-wave QBLK=128, XCD-grouped ------
__global__ void __launch_bounds__(512) attn_kernel(const unsigned short* __restrict__ q,
                                                   const unsigned short* __restrict__ k,
                                                   const unsigned short* __restrict__ vt,
                                                   unsigned short* __restrict__ o) {
    __shared__ alignas(16) unsigned short Kl[2][64 * 64];
    __shared__ alignas(16) unsigned short Vl[2][64 * 64];
    __shared__ alignas(16) unsigned short Pl[8][16 * PQ];
    const int pid = blockIdx.x;
    const int g = (pid >> 6) * 8 + (pid & 7);
    const int qt = (pid >> 3) & 7;
    const int b = g >> 3, h = g & 7;
    const int t = threadIdx.x, lane = t & 63, w = t >> 6;
    const int l15 = lane & 15, l4 = lane >> 4;

    const float QSC = 0.125f * 1.44269504f;
    const int qrow = qt * 128 + w * 16 + l15;
    const unsigned short* qp = q + ((size_t)(b * SS + qrow)) * 512 + h * 64;
    bf16x8 qf[2];
#pragma unroll
    for (int kk = 0; kk < 2; ++kk) {
        bf16x8 tmp = *(const bf16x8*)(qp + kk * 32 + l4 * 8);
#pragma unroll
        for (int e = 0; e < 8; ++e)
            tmp[e] = (short)f2b(b2f((unsigned short)tmp[e]) * QSC);
        qf[kk] = tmp;
    }

    const int srow = t >> 3;
    const int scb = ((t & 7) * 16) ^ ((srow & 7) << 4);
    const char* kptr = (const char*)(k + ((size_t)(b * SS) + srow) * 512 + h * 64) + scb;
    const char* vptr = (const char*)(vt + ((size_t)(b * NH + h) * DK + srow) * SS) + scb;

    float m_run = -1e30f, l_run = 0.f;
    f32x4 acc_o[4];
    const f32x4 z4 = {0.f, 0.f, 0.f, 0.f};
#pragma unroll
    for (int j = 0; j < 4; ++j) acc_o[j] = z4;

    gload16(kptr, &Kl[0][t * 8]);
    gload16(vptr, &Vl[0][t * 8]);
    kptr += 64 * 512 * 2;
    vptr += 64 * 2;
    __syncthreads();

#pragma unroll 1
    for (int kt = 0; kt < 16; ++kt) {
        const int bi = kt & 1;
        if (kt < 15) {
            gload16(kptr, &Kl[bi ^ 1][t * 8]);
            gload16(vptr, &Vl[bi ^ 1][t * 8]);
            kptr += 64 * 512 * 2;
            vptr += 64 * 2;
        }

        f32x4 sc[4];
#pragma unroll
        for (int j = 0; j < 4; ++j) sc[j] = z4;
#pragma unroll
        for (int kk = 0; kk < 2; ++kk)
#pragma unroll
            for (int j = 0; j < 4; ++j) {
                int row = j * 16 + l15;
                int cb = (kk * 64 + l4 * 16) ^ ((row & 7) << 4);
                bf16x8 kf = *(const bf16x8*)((const char*)Kl[bi] + row * 128 + cb);
                sc[j] = mfma16(kf, qf[kk], sc[j]);
            }

        float mx = fmaxf(fmaxf(sc[0][0], sc[0][1]), fmaxf(sc[0][2], sc[0][3]));
#pragma unroll
        for (int j = 1; j < 4; ++j)
            mx = fmaxf(mx, fmaxf(fmaxf(sc[j][0], sc[j][1]), fmaxf(sc[j][2], sc[j][3])));
        mx = fmaxf(mx, __shfl_xor(mx, 16));
        mx = fmaxf(mx, __shfl_xor(mx, 32));
        const float mnew = fmaxf(m_run, mx);
        const float scl = fexp2(m_run - mnew);
        m_run = mnew;

        float p[4][4], lsum = 0.f;
#pragma unroll
        for (int j = 0; j < 4; ++j)
#pragma unroll
            for (int r = 0; r < 4; ++r) {
                p[j][r] = fexp2(sc[j][r] - mnew);
                lsum += p[j][r];
            }
        l_run = l_run * scl + lsum;

#pragma unroll
        for (int j = 0; j < 4; ++j) {
            uint2 pk;
            pk.x = cvtpk(p[j][0], p[j][1]);
            pk.y = cvtpk(p[j][2], p[j][3]);
            *(uint2*)&Pl[w][l15 * PQ + j * 16 + l4 * 4] = pk;
        }

        float scl_r[4];
#pragma unroll
        for (int r = 0; r < 4; ++r) scl_r[r] = __shfl(scl, (l4 << 2) | r);
#pragma unroll
        for (int j = 0; j < 4; ++j)
#pragma unroll
            for (int r = 0; r < 4; ++r) acc_o[j][r] *= scl_r[r];

#pragma unroll
        for (int kk = 0; kk < 2; ++kk) {
            bf16x8 pf = *(const bf16x8*)&Pl[w][l15 * PQ + kk * 32 + l4 * 8];
#pragma unroll
            for (int j = 0; j < 4; ++j) {
                int row = j * 16 + l15;
                int cb = (kk * 64 + l4 * 16) ^ ((row & 7) << 4);
                bf16x8 vf = *(const bf16x8*)((const char*)Vl[bi] + row * 128 + cb);
                acc_o[j] = mfma16(pf, vf, acc_o[j]);
            }
        }

        __syncthreads();
    }

    float l_tot = l_run;
    l_tot += __shfl_xor(l_tot, 16);
    l_tot += __shfl_xor(l_tot, 32);
    float l_r[4];
#pragma unroll
    for (int r = 0; r < 4; ++r) l_r[r] = __shfl(l_tot, (l4 << 2) | r);

#pragma unroll
    for (int j = 0; j < 4; ++j)
#pragma unroll
        for (int r = 0; r < 4; ++r) {
            int row = qt * 128 + w * 16 + l4 * 4 + r;
            float val = acc_o[j][r] / l_r[r];
            o[((size_t)(b * SS + row)) * 512 + h * 64 + j * 16 + l15] = f2b(val);
        }
}

// ---------------- output projection + bias + residual, XCD-grouped by m-tile ---------
__global__ void __launch_bounds__(256) gemm_out_kernel(const unsigned short* __restrict__ ao,
                                                       const unsigned short* __restrict__ woT,
                                                       const float* __restrict__ bo,
                                                       const unsigned short* __restrict__ xt,
                                                       float* __restrict__ out) {
    __shared__ alignas(16) unsigned short A_lds[2][128 * 64];
    __shared__ alignas(16) unsigned short B_lds[2][128 * 64];
    const int pid = blockIdx.x;                  // 0..255
    const int xcd = pid & 7, rest = pid >> 3;    // rest 0..31
    const int n0 = (rest & 3) * 128;
    const int m0 = (xcd + (rest >> 2) * 8) * 128;
    f32x4 acc[4][4];
    const f32x4 z4 = {0.f, 0.f, 0.f, 0.f};
#pragma unroll
    for (int i = 0; i < 4; ++i)
#pragma unroll
        for (int j = 0; j < 4; ++j) acc[i][j] = z4;
    gemm_tile<true>(ao, woT, m0, n0, A_lds, B_lds, acc);
    const int lane = threadIdx.x & 63, w = threadIdx.x >> 6;
    const int l15 = lane & 15, l4 = lane >> 4;
    const int wm = (w >> 1) * 64, wn = (w & 1) * 64;
    float4 bias4[4];
#pragma unroll
    for (int j = 0; j < 4; ++j)
        bias4[j] = *(const float4*)(bo + n0 + wn + j * 16 + l4 * 4);
#pragma unroll
    for (int i = 0; i < 4; ++i) {
        const size_t row = (size_t)(m0 + wm + i * 16 + l15);
#pragma unroll
        for (int j = 0; j < 4; ++j) {
            const int nc = n0 + wn + j * 16 + l4 * 4;
            uint2 rv = *(const uint2*)&xt[row * 512 + nc];
            float4 o4;
            o4.x = acc[i][j][0] + bias4[j].x + b2f((unsigned short)(rv.x & 0xffff));
            o4.y = acc[i][j][1] + bias4[j].y + b2f((unsigned short)(rv.x >> 16));
            o4.z = acc[i][j][2] + bias4[j].z + b2f((unsigned short)(rv.y & 0xffff));
            o4.w = acc[i][j][3] + bias4[j].w + b2f((unsigned short)(rv.y >> 16));
            *(float4*)&out[row * 512 + nc] = o4;
        }
    }
}

extern "C" void kernel_launch(void* const* d_in, const int* in_sizes, int n_in,
                              void* d_out, int out_size, void* d_ws, size_t ws_size,
                              hipStream_t stream) {
    const float* x   = (const float*)d_in[0];
    const float* wq  = (const float*)d_in[1];
    const float* bq  = (const float*)d_in[2];
    const float* wk  = (const float*)d_in[3];
    const float* bk  = (const float*)d_in[4];
    const float* wv  = (const float*)d_in[5];
    const float* bv  = (const float*)d_in[6];
    const float* lng = (const float*)d_in[7];
    const float* lnb = (const float*)d_in[8];
    const float* wo  = (const float*)d_in[9];
    const float* bo  = (const float*)d_in[10];
    float* out = (float*)d_out;

    unsigned short* ws  = (unsigned short*)d_ws;
    const size_t M1 = (size_t)1024 * 1024;
    unsigned short* tn   = ws;               // 4M elems (8 MB); reused as ao after qkv
    unsigned short* qkvb = ws + 4 * M1;      // q @ +0, k @ +4M, vt @ +8M (24 MB)
    unsigned short* wT   = ws + 16 * M1;     // 1M elems (2 MB)
    unsigned short* xt   = ws + 17 * M1;     // 4M elems (8 MB)
    unsigned short* ao   = tn;

    prep_kernel<<<512, 256, 0, stream>>>(wq, wk, wv, wo, wT, x, lng, lnb, xt, tn);
    gemm_qkvf_kernel<<<512, 256, 0, stream>>>(tn, wT, bq, bk, bv, qkvb);
    attn_kernel<<<512, 512, 0, stream>>>(qkvb,
                                         qkvb + (size_t)MM * 512,
                                         qkvb + (size_t)2 * MM * 512,
                                         ao);
    gemm_out_kernel<<<256, 256, 0, stream>>>(ao, wT + (size_t)3 * 512 * 512, bo, xt, out);
}